// Round 7
// baseline (28.505 us; speedup 1.0000x reference)
//
#include <hip/hip_runtime.h>

// Problem constants
#define BB    32
#define N_OPC 512
#define N_MAC 64
#define FF    8
#define HH    128
#define OO    8
#define TM    32      // rows per block
#define ASTRB 136     // activation plane row stride (ushorts), 272B

typedef __bf16 bf16x8 __attribute__((ext_vector_type(8)));
typedef __bf16 bf16x4 __attribute__((ext_vector_type(4)));
typedef float  f32x4  __attribute__((ext_vector_type(4)));

// ws layout (ushort offsets). Frag element: frag[(jt*KS+ks)*64+lane][i] =
//   W[k = ks*32 + (lane>>4)*8 + i][j = jt*16 + (lane&15)], zero-padded.
// Used as the MFMA *A* operand (weights-as-A swapped form).
#define WS_W2HI 0        // L*16384, L: 0=l0w2 1=l1w2 2=pw2   (8 jt x 4 ks)
#define WS_W2LO 49152
#define WS_W3HI 98304    // L*2048,  L: 0=l0w3 1=l1w3 2=pw3   (1 jt x 4 ks, cols padded to 16)
#define WS_W3LO 104448
#define WS_W1HI 110592   // L*4096,  L: 0=l0w1 1=l1w1 2=pw1   (8 jt x 1 ks, K padded to 32)
#define WS_W1LO 122880

__device__ __forceinline__ float elu_f(float x) {
    return x > 0.0f ? x : (__expf(x) - 1.0f);
}
__device__ __forceinline__ void split2(float v, __bf16& h, __bf16& l) {
    h = (__bf16)v;
    l = (__bf16)(v - (float)h);
}
__device__ __forceinline__ void split_store_scalar(float v, ushort* hi, ushort* lo, int off) {
    __bf16 h, l; split2(v, h, l);
    hi[off] = __builtin_bit_cast(ushort, h);
    lo[off] = __builtin_bit_cast(ushort, l);
}

// ---- weight prep: fp32 -> bf16 hi/lo fragments ----
__global__ void prep_kernel(const float* __restrict__ w20, const float* __restrict__ w21,
                            const float* __restrict__ w22,
                            const float* __restrict__ w30, const float* __restrict__ w31,
                            const float* __restrict__ w32,
                            const float* __restrict__ w10, const float* __restrict__ w11,
                            const float* __restrict__ w12,
                            ushort* __restrict__ ws)
{
    const int gid = blockIdx.x * 256 + threadIdx.x;
    if (gid < 3 * 16384) {                       // W2: 128x128
        const int layer = gid >> 14, idx = gid & 16383;
        const float* w = layer == 0 ? w20 : layer == 1 ? w21 : w22;
        const int k = idx >> 7, j = idx & 127;
        const float x = w[idx];
        const int ks = k >> 5, kk = k & 31, jt = j >> 4, jj = j & 15;
        const int lane = ((kk >> 3) << 4) | jj, i = kk & 7;
        const int off = (((jt * 4 + ks) * 64 + lane) << 3) + i;
        __bf16 h, l; split2(x, h, l);
        ws[WS_W2HI + layer * 16384 + off] = __builtin_bit_cast(ushort, h);
        ws[WS_W2LO + layer * 16384 + off] = __builtin_bit_cast(ushort, l);
    } else if (gid < 3 * 16384 + 3 * 2048) {     // W3: 128x8 padded to 16 cols
        const int g2 = gid - 3 * 16384;
        const int layer = g2 >> 11, idx = g2 & 2047;
        const float* w = layer == 0 ? w30 : layer == 1 ? w31 : w32;
        const int i = idx & 7, lane = (idx >> 3) & 63, ks = idx >> 9;
        const int k = ks * 32 + (lane >> 4) * 8 + i, j = lane & 15;
        const float x = (j < OO) ? w[k * OO + j] : 0.0f;
        __bf16 h, l; split2(x, h, l);
        ws[WS_W3HI + layer * 2048 + idx] = __builtin_bit_cast(ushort, h);
        ws[WS_W3LO + layer * 2048 + idx] = __builtin_bit_cast(ushort, l);
    } else {                                     // W1: Kx128, K padded to 32
        const int g1 = gid - (3 * 16384 + 3 * 2048);
        const int layer = g1 >> 12, idx = g1 & 4095;
        const float* w = layer == 0 ? w10 : layer == 1 ? w11 : w12;
        const int i = idx & 7, lane = (idx >> 3) & 63, jt = idx >> 9;
        const int k = (lane >> 4) * 8 + i, j = jt * 16 + (lane & 15);
        const int Kr = (layer == 2) ? 16 : 8;
        const float x = (k < Kr) ? w[k * HH + j] : 0.0f;
        __bf16 h, l; split2(x, h, l);
        ws[WS_W1HI + layer * 4096 + idx] = __builtin_bit_cast(ushort, h);
        ws[WS_W1LO + layer * 4096 + idx] = __builtin_bit_cast(ushort, l);
    }
}

// epilogue: acc (4 consecutive output features) + bias -> elu -> split -> 2x ds_write_b64
__device__ __forceinline__ void epi_store(f32x4 a, const float* __restrict__ bias, int jb,
                                          ushort* __restrict__ dH, ushort* __restrict__ dL,
                                          int off)
{
    const float4 bb = *(const float4*)(bias + jb);
    bf16x4 vh, vl;
    {
        float v0 = elu_f(a[0] + bb.x), v1 = elu_f(a[1] + bb.y);
        float v2 = elu_f(a[2] + bb.z), v3 = elu_f(a[3] + bb.w);
        __bf16 h, l;
        split2(v0, h, l); vh[0] = h; vl[0] = l;
        split2(v1, h, l); vh[1] = h; vl[1] = l;
        split2(v2, h, l); vh[2] = h; vl[2] = l;
        split2(v3, h, l); vh[3] = h; vl[3] = l;
    }
    *(bf16x4*)(dH + off) = vh;
    *(bf16x4*)(dL + off) = vl;
}

__global__ __launch_bounds__(256, 4) void mlps_kernel(
    const int*   __restrict__ adj,
    const float* __restrict__ fop,
    const float* __restrict__ fmab,
    const float* __restrict__ l0b1, const float* __restrict__ l0b2, const float* __restrict__ l0b3,
    const float* __restrict__ l1b1, const float* __restrict__ l1b2, const float* __restrict__ l1b3,
    const float* __restrict__ pb1,  const float* __restrict__ pb2,  const float* __restrict__ pb3,
    const ushort* __restrict__ wsf,
    float* __restrict__ out)
{
    __shared__ __align__(16) ushort buf[2][2][TM * ASTRB];    // [br][hi/lo] 34.8 KB, reused in place
    __shared__ __align__(16) ushort xinH[TM * FF], xinL[TM * FF];
    __shared__ __align__(16) ushort catH[TM * 16], catL[TM * 16];

    const int tid  = threadIdx.x;
    const int wv   = tid >> 6;        // 0..3
    const int lane = tid & 63;
    const int lrow = lane & 15;       // activation row within 16-row tile
    const int lk   = lane >> 4;       // k-octet / output-feature quad
    const int row0 = blockIdx.x * TM;
    const int b    = row0 / N_OPC;
    const int br   = wv >> 1;         // branch for P1/P2
    const int jh   = wv & 1;          // jtile half for P1/P2

    // ---- prefetch (before P0): P1 weight frags + br1 activations from global
    bf16x8 w1h[4], w1l[4];
    {
        const bf16x8* WH = (const bf16x8*)(wsf + WS_W1HI + br * 4096);
        const bf16x8* WL = (const bf16x8*)(wsf + WS_W1LO + br * 4096);
        #pragma unroll
        for (int jt = 0; jt < 4; ++jt) {
            w1h[jt] = WH[(jh * 4 + jt) * 64 + lane];
            w1l[jt] = WL[(jh * 4 + jt) * 64 + lane];
        }
    }
    bf16x8 XH[2] = {}, XL[2] = {};
    if (br == 1 && lk == 0) {
        #pragma unroll
        for (int rt = 0; rt < 2; ++rt) {
            const float* src = fop + (row0 + rt * 16 + lrow) * FF;
            const float4 f0 = *(const float4*)src;
            const float4 f1 = *(const float4*)(src + 4);
            __bf16 h, l;
            split2(f0.x, h, l); XH[rt][0] = h; XL[rt][0] = l;
            split2(f0.y, h, l); XH[rt][1] = h; XL[rt][1] = l;
            split2(f0.z, h, l); XH[rt][2] = h; XL[rt][2] = l;
            split2(f0.w, h, l); XH[rt][3] = h; XL[rt][3] = l;
            split2(f1.x, h, l); XH[rt][4] = h; XL[rt][4] = l;
            split2(f1.y, h, l); XH[rt][5] = h; XL[rt][5] = l;
            split2(f1.z, h, l); XH[rt][6] = h; XL[rt][6] = l;
            split2(f1.w, h, l); XH[rt][7] = h; XL[rt][7] = l;
        }
    }

    // ---- P0: aggregation xin[r][f] = sum_m adj[r][m]*fm[m][f]  (all 256 threads)
    {
        const int r = tid >> 3, f = tid & 7;
        const int* arow = adj + (row0 + r) * N_MAC;
        const float* fm = fmab + b * N_MAC * FF + f;
        float a = 0.0f;
        #pragma unroll
        for (int m4 = 0; m4 < N_MAC; m4 += 4) {
            const int4 av = *(const int4*)(arow + m4);
            a = fmaf((float)av.x, fm[(m4 + 0) * FF], a);
            a = fmaf((float)av.y, fm[(m4 + 1) * FF], a);
            a = fmaf((float)av.z, fm[(m4 + 2) * FF], a);
            a = fmaf((float)av.w, fm[(m4 + 3) * FF], a);
        }
        split_store_scalar(a, xinH, xinL, tid);
    }
    __syncthreads();

    // ---- P1: input layers (K=8/pad32). wave=(br,jh): 4 jtiles x 2 rowtiles
    {
        if (br == 0 && lk == 0) {
            #pragma unroll
            for (int rt = 0; rt < 2; ++rt) {
                XH[rt] = *(const bf16x8*)(xinH + (rt * 16 + lrow) * FF);
                XL[rt] = *(const bf16x8*)(xinL + (rt * 16 + lrow) * FF);
            }
        }
        f32x4 acc[4][2] = {};
        #pragma unroll
        for (int jt = 0; jt < 4; ++jt)
            #pragma unroll
            for (int rt = 0; rt < 2; ++rt) {
                acc[jt][rt] = __builtin_amdgcn_mfma_f32_16x16x32_bf16(w1h[jt], XH[rt], acc[jt][rt], 0, 0, 0);
                acc[jt][rt] = __builtin_amdgcn_mfma_f32_16x16x32_bf16(w1l[jt], XH[rt], acc[jt][rt], 0, 0, 0);
                acc[jt][rt] = __builtin_amdgcn_mfma_f32_16x16x32_bf16(w1h[jt], XL[rt], acc[jt][rt], 0, 0, 0);
            }
        const float* b1 = br ? l1b1 : l0b1;
        ushort* dH = buf[br][0];
        ushort* dL = buf[br][1];
        #pragma unroll
        for (int jt = 0; jt < 4; ++jt) {
            const int jb = (jh * 4 + jt) * 16 + lk * 4;
            #pragma unroll
            for (int rt = 0; rt < 2; ++rt)
                epi_store(acc[jt][rt], b1, jb, dH, dL, (rt * 16 + lrow) * ASTRB + jb);
        }
    }
    __syncthreads();

    // ---- P2: heavy layers (128x128). wave=(br,jh): 4 jtiles x 2 rowtiles, in-place
    {
        const ushort* aH = buf[br][0];
        const ushort* aL = buf[br][1];
        const bf16x8* WH = (const bf16x8*)(wsf + WS_W2HI + br * 16384);
        const bf16x8* WL = (const bf16x8*)(wsf + WS_W2LO + br * 16384);
        f32x4 acc[4][2] = {};
        #pragma unroll
        for (int ks = 0; ks < 4; ++ks) {
            bf16x8 xh[2], xl[2];
            #pragma unroll
            for (int rt = 0; rt < 2; ++rt) {
                const int ab = (rt * 16 + lrow) * ASTRB + ks * 32 + lk * 8;
                xh[rt] = *(const bf16x8*)(aH + ab);
                xl[rt] = *(const bf16x8*)(aL + ab);
            }
            #pragma unroll
            for (int jt = 0; jt < 4; ++jt) {
                const bf16x8 wh = WH[((jh * 4 + jt) * 4 + ks) * 64 + lane];
                const bf16x8 wl = WL[((jh * 4 + jt) * 4 + ks) * 64 + lane];
                #pragma unroll
                for (int rt = 0; rt < 2; ++rt) {
                    acc[jt][rt] = __builtin_amdgcn_mfma_f32_16x16x32_bf16(wh, xh[rt], acc[jt][rt], 0, 0, 0);
                    acc[jt][rt] = __builtin_amdgcn_mfma_f32_16x16x32_bf16(wl, xh[rt], acc[jt][rt], 0, 0, 0);
                    acc[jt][rt] = __builtin_amdgcn_mfma_f32_16x16x32_bf16(wh, xl[rt], acc[jt][rt], 0, 0, 0);
                }
            }
        }
        __syncthreads();               // all reads of buf[br] complete
        const float* b2 = br ? l1b2 : l0b2;
        ushort* dH = buf[br][0];
        ushort* dL = buf[br][1];
        #pragma unroll
        for (int jt = 0; jt < 4; ++jt) {
            const int jb = (jh * 4 + jt) * 16 + lk * 4;
            #pragma unroll
            for (int rt = 0; rt < 2; ++rt)
                epi_store(acc[jt][rt], b2, jb, dH, dL, (rt * 16 + lrow) * ASTRB + jb);
        }
    }
    __syncthreads();

    // ---- P3: branch output layers (128 -> 8 pad 16). wave=(br3, rt3)
    {
        const int br3 = wv >> 1, rt3 = wv & 1;
        const ushort* aH = buf[br3][0];
        const ushort* aL = buf[br3][1];
        const bf16x8* WH = (const bf16x8*)(wsf + WS_W3HI + br3 * 2048);
        const bf16x8* WL = (const bf16x8*)(wsf + WS_W3LO + br3 * 2048);
        f32x4 acc = {};
        #pragma unroll
        for (int ks = 0; ks < 4; ++ks) {
            const int ab = (rt3 * 16 + lrow) * ASTRB + ks * 32 + lk * 8;
            const bf16x8 xh = *(const bf16x8*)(aH + ab);
            const bf16x8 xl = *(const bf16x8*)(aL + ab);
            const bf16x8 wh = WH[ks * 64 + lane];
            const bf16x8 wl = WL[ks * 64 + lane];
            acc = __builtin_amdgcn_mfma_f32_16x16x32_bf16(wh, xh, acc, 0, 0, 0);
            acc = __builtin_amdgcn_mfma_f32_16x16x32_bf16(wl, xh, acc, 0, 0, 0);
            acc = __builtin_amdgcn_mfma_f32_16x16x32_bf16(wh, xl, acc, 0, 0, 0);
        }
        if (lk < 2) {
            const float* b3 = br3 ? l1b3 : l0b3;
            epi_store(acc, b3, lk * 4, catH, catL,
                      (rt3 * 16 + lrow) * 16 + br3 * OO + lk * 4);
        }
    }
    __syncthreads();

    // ---- P4: proj input layer (K=16 pad 32). wave wv: jtiles wv*2..+1, 2 rowtiles
    {
        const bf16x8* WH = (const bf16x8*)(wsf + WS_W1HI + 2 * 4096);
        const bf16x8* WL = (const bf16x8*)(wsf + WS_W1LO + 2 * 4096);
        bf16x8 CH[2] = {}, CL[2] = {};
        if (lk < 2) {
            #pragma unroll
            for (int rt = 0; rt < 2; ++rt) {
                CH[rt] = *(const bf16x8*)(catH + (rt * 16 + lrow) * 16 + lk * 8);
                CL[rt] = *(const bf16x8*)(catL + (rt * 16 + lrow) * 16 + lk * 8);
            }
        }
        f32x4 acc[2][2] = {};
        #pragma unroll
        for (int jtl = 0; jtl < 2; ++jtl) {
            const bf16x8 wh = WH[(wv * 2 + jtl) * 64 + lane];
            const bf16x8 wl = WL[(wv * 2 + jtl) * 64 + lane];
            #pragma unroll
            for (int rt = 0; rt < 2; ++rt) {
                acc[jtl][rt] = __builtin_amdgcn_mfma_f32_16x16x32_bf16(wh, CH[rt], acc[jtl][rt], 0, 0, 0);
                acc[jtl][rt] = __builtin_amdgcn_mfma_f32_16x16x32_bf16(wl, CH[rt], acc[jtl][rt], 0, 0, 0);
                acc[jtl][rt] = __builtin_amdgcn_mfma_f32_16x16x32_bf16(wh, CL[rt], acc[jtl][rt], 0, 0, 0);
            }
        }
        #pragma unroll
        for (int jtl = 0; jtl < 2; ++jtl) {
            const int jb = (wv * 2 + jtl) * 16 + lk * 4;
            #pragma unroll
            for (int rt = 0; rt < 2; ++rt)
                epi_store(acc[jtl][rt], pb1, jb, buf[0][0], buf[0][1],
                          (rt * 16 + lrow) * ASTRB + jb);
        }
    }
    __syncthreads();

    // ---- P5: proj heavy layer. wave wv: jtiles wv*2..+1, 2 rowtiles; write buf[1]
    {
        const ushort* aH = buf[0][0];
        const ushort* aL = buf[0][1];
        const bf16x8* WH = (const bf16x8*)(wsf + WS_W2HI + 2 * 16384);
        const bf16x8* WL = (const bf16x8*)(wsf + WS_W2LO + 2 * 16384);
        f32x4 acc[2][2] = {};
        #pragma unroll
        for (int ks = 0; ks < 4; ++ks) {
            bf16x8 xh[2], xl[2];
            #pragma unroll
            for (int rt = 0; rt < 2; ++rt) {
                const int ab = (rt * 16 + lrow) * ASTRB + ks * 32 + lk * 8;
                xh[rt] = *(const bf16x8*)(aH + ab);
                xl[rt] = *(const bf16x8*)(aL + ab);
            }
            #pragma unroll
            for (int jtl = 0; jtl < 2; ++jtl) {
                const bf16x8 wh = WH[((wv * 2 + jtl) * 4 + ks) * 64 + lane];
                const bf16x8 wl = WL[((wv * 2 + jtl) * 4 + ks) * 64 + lane];
                #pragma unroll
                for (int rt = 0; rt < 2; ++rt) {
                    acc[jtl][rt] = __builtin_amdgcn_mfma_f32_16x16x32_bf16(wh, xh[rt], acc[jtl][rt], 0, 0, 0);
                    acc[jtl][rt] = __builtin_amdgcn_mfma_f32_16x16x32_bf16(wl, xh[rt], acc[jtl][rt], 0, 0, 0);
                    acc[jtl][rt] = __builtin_amdgcn_mfma_f32_16x16x32_bf16(wh, xl[rt], acc[jtl][rt], 0, 0, 0);
                }
            }
        }
        #pragma unroll
        for (int jtl = 0; jtl < 2; ++jtl) {
            const int jb = (wv * 2 + jtl) * 16 + lk * 4;
            #pragma unroll
            for (int rt = 0; rt < 2; ++rt)
                epi_store(acc[jtl][rt], pb2, jb, buf[1][0], buf[1][1],
                          (rt * 16 + lrow) * ASTRB + jb);
        }
    }
    __syncthreads();

    // ---- P6: proj output layer (128 -> 8). waves 0,1 -> rowtiles, dwordx4 store
    if (wv < 2) {
        const int rt = wv;
        const ushort* aH = buf[1][0];
        const ushort* aL = buf[1][1];
        const bf16x8* WH = (const bf16x8*)(wsf + WS_W3HI + 2 * 2048);
        const bf16x8* WL = (const bf16x8*)(wsf + WS_W3LO + 2 * 2048);
        f32x4 acc = {};
        #pragma unroll
        for (int ks = 0; ks < 4; ++ks) {
            const int ab = (rt * 16 + lrow) * ASTRB + ks * 32 + lk * 8;
            const bf16x8 xh = *(const bf16x8*)(aH + ab);
            const bf16x8 xl = *(const bf16x8*)(aL + ab);
            const bf16x8 wh = WH[ks * 64 + lane];
            const bf16x8 wl = WL[ks * 64 + lane];
            acc = __builtin_amdgcn_mfma_f32_16x16x32_bf16(wh, xh, acc, 0, 0, 0);
            acc = __builtin_amdgcn_mfma_f32_16x16x32_bf16(wl, xh, acc, 0, 0, 0);
            acc = __builtin_amdgcn_mfma_f32_16x16x32_bf16(wh, xl, acc, 0, 0, 0);
        }
        if (lk < 2) {
            const float4 bb = *(const float4*)(pb3 + lk * 4);
            float4 o;
            o.x = acc[0] + bb.x; o.y = acc[1] + bb.y;
            o.z = acc[2] + bb.z; o.w = acc[3] + bb.w;
            *(float4*)(out + (row0 + rt * 16 + lrow) * OO + lk * 4) = o;
        }
    }
}

extern "C" void kernel_launch(void* const* d_in, const int* in_sizes, int n_in,
                              void* d_out, int out_size, void* d_ws, size_t ws_size,
                              hipStream_t stream) {
    (void)in_sizes; (void)n_in; (void)out_size; (void)ws_size;
    const int*   adj  = (const int*)  d_in[0];
    const float* fop  = (const float*)d_in[1];
    const float* fmab = (const float*)d_in[2];
    const float* l0w1 = (const float*)d_in[3];
    const float* l0b1 = (const float*)d_in[4];
    const float* l0w2 = (const float*)d_in[5];
    const float* l0b2 = (const float*)d_in[6];
    const float* l0w3 = (const float*)d_in[7];
    const float* l0b3 = (const float*)d_in[8];
    const float* l1w1 = (const float*)d_in[9];
    const float* l1b1 = (const float*)d_in[10];
    const float* l1w2 = (const float*)d_in[11];
    const float* l1b2 = (const float*)d_in[12];
    const float* l1w3 = (const float*)d_in[13];
    const float* l1b3 = (const float*)d_in[14];
    const float* pw1  = (const float*)d_in[15];
    const float* pb1  = (const float*)d_in[16];
    const float* pw2  = (const float*)d_in[17];
    const float* pb2  = (const float*)d_in[18];
    const float* pw3  = (const float*)d_in[19];
    const float* pb3  = (const float*)d_in[20];
    float* out = (float*)d_out;
    ushort* wsf = (ushort*)d_ws;

    prep_kernel<<<dim3(264), dim3(256), 0, stream>>>(
        l0w2, l1w2, pw2, l0w3, l1w3, pw3, l0w1, l1w1, pw1, wsf);

    const int grid = (BB * N_OPC) / TM;   // 512
    mlps_kernel<<<dim3(grid), dim3(256), 0, stream>>>(
        adj, fop, fmab,
        l0b1, l0b2, l0b3,
        l1b1, l1b2, l1b3,
        pb1, pb2, pb3,
        wsf, out);
}

// Round 8
// 20.041 us; speedup vs baseline: 1.4223x; 1.4223x over previous
//
#include <hip/hip_runtime.h>

// Problem constants
#define BB    32
#define N_OPC 512
#define N_MAC 64
#define FF    8
#define HH    128
#define OO    8
#define TM    32      // rows per block
#define ASTRB 136     // activation plane row stride (ushorts), 272B

typedef _Float16 f16x8 __attribute__((ext_vector_type(8)));
typedef _Float16 f16x4 __attribute__((ext_vector_type(4)));
typedef float    f32x4 __attribute__((ext_vector_type(4)));

// ws layout (ushort offsets), fp16 single plane. Frag element:
//   frag[(jt*KS+ks)*64+lane][i] = W[k = ks*32+(lane>>4)*8+i][j = jt*16+(lane&15)], zero-padded.
// Used as the MFMA *A* operand (weights-as-A swapped form).
#define WS_W2 0        // L*16384, L: 0=l0w2 1=l1w2 2=pw2   (8 jt x 4 ks)
#define WS_W3 49152    // L*2048,  L: 0=l0w3 1=l1w3 2=pw3   (1 jt x 4 ks, cols padded to 16)
#define WS_W1 55296    // L*4096,  L: 0=l0w1 1=l1w1 2=pw1   (8 jt x 1 ks, K padded to 32)

__device__ __forceinline__ float elu_f(float x) {
    return x > 0.0f ? x : (__expf(x) - 1.0f);
}
// split v into hi/lo fp16
__device__ __forceinline__ void split2h(float v, _Float16& h, _Float16& l) {
    h = (_Float16)v;
    l = (_Float16)(v - (float)h);
}
__device__ __forceinline__ void split_store_scalar(float v, ushort* hi, ushort* lo, int off) {
    _Float16 h, l; split2h(v, h, l);
    hi[off] = __builtin_bit_cast(ushort, h);
    lo[off] = __builtin_bit_cast(ushort, l);
}

// ---- weight prep: fp32 -> fp16 fragments (single plane) ----
__global__ void prep_kernel(const float* __restrict__ w20, const float* __restrict__ w21,
                            const float* __restrict__ w22,
                            const float* __restrict__ w30, const float* __restrict__ w31,
                            const float* __restrict__ w32,
                            const float* __restrict__ w10, const float* __restrict__ w11,
                            const float* __restrict__ w12,
                            ushort* __restrict__ ws)
{
    const int gid = blockIdx.x * 256 + threadIdx.x;
    if (gid < 3 * 16384) {                       // W2: 128x128
        const int layer = gid >> 14, idx = gid & 16383;
        const float* w = layer == 0 ? w20 : layer == 1 ? w21 : w22;
        const int k = idx >> 7, j = idx & 127;
        const float x = w[idx];
        const int ks = k >> 5, kk = k & 31, jt = j >> 4, jj = j & 15;
        const int lane = ((kk >> 3) << 4) | jj, i = kk & 7;
        const int off = (((jt * 4 + ks) * 64 + lane) << 3) + i;
        const _Float16 h = (_Float16)x;
        ws[WS_W2 + layer * 16384 + off] = __builtin_bit_cast(ushort, h);
    } else if (gid < 3 * 16384 + 3 * 2048) {     // W3: 128x8 padded to 16 cols
        const int g2 = gid - 3 * 16384;
        const int layer = g2 >> 11, idx = g2 & 2047;
        const float* w = layer == 0 ? w30 : layer == 1 ? w31 : w32;
        const int i = idx & 7, lane = (idx >> 3) & 63, ks = idx >> 9;
        const int k = ks * 32 + (lane >> 4) * 8 + i, j = lane & 15;
        const float x = (j < OO) ? w[k * OO + j] : 0.0f;
        const _Float16 h = (_Float16)x;
        ws[WS_W3 + layer * 2048 + idx] = __builtin_bit_cast(ushort, h);
    } else {                                     // W1: Kx128, K padded to 32
        const int g1 = gid - (3 * 16384 + 3 * 2048);
        const int layer = g1 >> 12, idx = g1 & 4095;
        const float* w = layer == 0 ? w10 : layer == 1 ? w11 : w12;
        const int i = idx & 7, lane = (idx >> 3) & 63, jt = idx >> 9;
        const int k = (lane >> 4) * 8 + i, j = jt * 16 + (lane & 15);
        const int Kr = (layer == 2) ? 16 : 8;
        const float x = (k < Kr) ? w[k * HH + j] : 0.0f;
        const _Float16 h = (_Float16)x;
        ws[WS_W1 + layer * 4096 + idx] = __builtin_bit_cast(ushort, h);
    }
}

// epilogue: acc (4 consecutive output features) + bias -> elu -> split -> 2x ds_write_b64
__device__ __forceinline__ void epi_store(f32x4 a, const float* __restrict__ bias, int jb,
                                          ushort* __restrict__ dH, ushort* __restrict__ dL,
                                          int off)
{
    const float4 bb = *(const float4*)(bias + jb);
    f16x4 vh, vl;
    {
        float v0 = elu_f(a[0] + bb.x), v1 = elu_f(a[1] + bb.y);
        float v2 = elu_f(a[2] + bb.z), v3 = elu_f(a[3] + bb.w);
        _Float16 h, l;
        split2h(v0, h, l); vh[0] = h; vl[0] = l;
        split2h(v1, h, l); vh[1] = h; vl[1] = l;
        split2h(v2, h, l); vh[2] = h; vl[2] = l;
        split2h(v3, h, l); vh[3] = h; vl[3] = l;
    }
    *(f16x4*)(dH + off) = vh;
    *(f16x4*)(dL + off) = vl;
}

__global__ __launch_bounds__(512, 4) void mlps_kernel(
    const int*   __restrict__ adj,
    const float* __restrict__ fop,
    const float* __restrict__ fmab,
    const float* __restrict__ l0b1, const float* __restrict__ l0b2, const float* __restrict__ l0b3,
    const float* __restrict__ l1b1, const float* __restrict__ l1b2, const float* __restrict__ l1b3,
    const float* __restrict__ pb1,  const float* __restrict__ pb2,  const float* __restrict__ pb3,
    const ushort* __restrict__ wsf,
    float* __restrict__ out)
{
    __shared__ __align__(16) ushort hbuf[2][2][TM * ASTRB];   // [br][hi/lo]
    __shared__ __align__(16) ushort gbuf[2][2][TM * ASTRB];
    __shared__ float fmS[N_MAC * FF];
    __shared__ __align__(16) ushort xinH[TM * FF], xinL[TM * FF];
    __shared__ __align__(16) ushort xopH[TM * FF], xopL[TM * FF];
    __shared__ __align__(16) ushort catH[TM * 16], catL[TM * 16];

    const int tid  = threadIdx.x;
    const int wv   = tid >> 6;
    const int lane = tid & 63;
    const int lrow = lane & 15;       // activation row within 16-row tile
    const int lk   = lane >> 4;       // k-octet / output-feature quad
    const int row0 = blockIdx.x * TM;
    const int b    = row0 / N_OPC;

    // ---- stage: machine feats (fp32), op feats (split planes)
    fmS[tid % (N_MAC * FF)] = fmab[b * N_MAC * FF + (tid % (N_MAC * FF))];
    if (tid < TM * FF)
        split_store_scalar(fop[row0 * FF + tid], xopH, xopL, tid);
    __syncthreads();

    // ---- aggregation: xin[r][f] = sum_m adj[r][m] * fm[m][f]
    if (tid < TM * FF) {
        const int r = tid >> 3, f = tid & 7;
        const int* arow = adj + (row0 + r) * N_MAC;
        float a = 0.0f;
        #pragma unroll
        for (int m4 = 0; m4 < N_MAC; m4 += 4) {
            const int4 av = *(const int4*)(arow + m4);
            a = fmaf((float)av.x, fmS[(m4 + 0) * FF + f], a);
            a = fmaf((float)av.y, fmS[(m4 + 1) * FF + f], a);
            a = fmaf((float)av.z, fmS[(m4 + 2) * FF + f], a);
            a = fmaf((float)av.w, fmS[(m4 + 3) * FF + f], a);
        }
        split_store_scalar(a, xinH, xinL, tid);
    }
    __syncthreads();

    // ---- input layers (K=8 pad 32): waves 0-3 br0, 4-7 br1; 2 jtiles, 2 rowtiles each
    {
        const int br = wv >> 2, jt0 = (wv & 3) * 2;
        const ushort* xH = br ? xopH : xinH;
        const ushort* xL = br ? xopL : xinL;
        const f16x8* WF = (const f16x8*)(wsf + WS_W1 + br * 4096);
        const float* b1 = br ? l1b1 : l0b1;
        f16x8 XH[2] = {}, XL[2] = {};
        if (lk == 0) {
            #pragma unroll
            for (int rt = 0; rt < 2; ++rt) {
                XH[rt] = *(const f16x8*)(xH + (rt * 16 + lrow) * 8);
                XL[rt] = *(const f16x8*)(xL + (rt * 16 + lrow) * 8);
            }
        }
        f32x4 acc[2][2] = {};
        #pragma unroll
        for (int jtl = 0; jtl < 2; ++jtl) {
            const f16x8 wh = WF[(jt0 + jtl) * 64 + lane];
            #pragma unroll
            for (int rt = 0; rt < 2; ++rt) {
                acc[jtl][rt] = __builtin_amdgcn_mfma_f32_16x16x32_f16(wh, XH[rt], acc[jtl][rt], 0, 0, 0);
                acc[jtl][rt] = __builtin_amdgcn_mfma_f32_16x16x32_f16(wh, XL[rt], acc[jtl][rt], 0, 0, 0);
            }
        }
        ushort* dH = hbuf[br][0];
        ushort* dL = hbuf[br][1];
        #pragma unroll
        for (int jtl = 0; jtl < 2; ++jtl) {
            const int jb = (jt0 + jtl) * 16 + lk * 4;
            #pragma unroll
            for (int rt = 0; rt < 2; ++rt)
                epi_store(acc[jtl][rt], b1, jb, dH, dL, (rt * 16 + lrow) * ASTRB + jb);
        }
    }
    __syncthreads();

    // ---- heavy layers (128x128): waves 0-3 br0, 4-7 br1; 2 jtiles x 2 rowtiles
    {
        const int br = wv >> 2, jt0 = (wv & 3) * 2;
        const ushort* aH = hbuf[br][0];
        const ushort* aL = hbuf[br][1];
        const f16x8* WF = (const f16x8*)(wsf + WS_W2 + br * 16384);
        f32x4 acc[2][2] = {};
        #pragma unroll
        for (int ks = 0; ks < 4; ++ks) {
            f16x8 xh[2], xl[2];
            #pragma unroll
            for (int rt = 0; rt < 2; ++rt) {
                const int ab = (rt * 16 + lrow) * ASTRB + ks * 32 + lk * 8;
                xh[rt] = *(const f16x8*)(aH + ab);
                xl[rt] = *(const f16x8*)(aL + ab);
            }
            #pragma unroll
            for (int jtl = 0; jtl < 2; ++jtl) {
                const f16x8 wh = WF[((jt0 + jtl) * 4 + ks) * 64 + lane];
                #pragma unroll
                for (int rt = 0; rt < 2; ++rt) {
                    acc[jtl][rt] = __builtin_amdgcn_mfma_f32_16x16x32_f16(wh, xh[rt], acc[jtl][rt], 0, 0, 0);
                    acc[jtl][rt] = __builtin_amdgcn_mfma_f32_16x16x32_f16(wh, xl[rt], acc[jtl][rt], 0, 0, 0);
                }
            }
        }
        const float* b2 = br ? l1b2 : l0b2;
        ushort* dH = gbuf[br][0];
        ushort* dL = gbuf[br][1];
        #pragma unroll
        for (int jtl = 0; jtl < 2; ++jtl) {
            const int jb = (jt0 + jtl) * 16 + lk * 4;
            #pragma unroll
            for (int rt = 0; rt < 2; ++rt)
                epi_store(acc[jtl][rt], b2, jb, dH, dL, (rt * 16 + lrow) * ASTRB + jb);
        }
    }
    __syncthreads();

    // ---- branch output layers (128 -> 8 pad 16): waves 0-3
    if (wv < 4) {
        const int br = wv >> 1, rt = wv & 1;
        const ushort* aH = gbuf[br][0];
        const ushort* aL = gbuf[br][1];
        const f16x8* WF = (const f16x8*)(wsf + WS_W3 + br * 2048);
        f32x4 acc = {};
        #pragma unroll
        for (int ks = 0; ks < 4; ++ks) {
            const int ab = (rt * 16 + lrow) * ASTRB + ks * 32 + lk * 8;
            const f16x8 xh = *(const f16x8*)(aH + ab);
            const f16x8 xl = *(const f16x8*)(aL + ab);
            const f16x8 wh = WF[ks * 64 + lane];
            acc = __builtin_amdgcn_mfma_f32_16x16x32_f16(wh, xh, acc, 0, 0, 0);
            acc = __builtin_amdgcn_mfma_f32_16x16x32_f16(wh, xl, acc, 0, 0, 0);
        }
        if (lk < 2) {   // valid output features j = lk*4 .. lk*4+3 (0..7)
            const float* b3 = br ? l1b3 : l0b3;
            epi_store(acc, b3, lk * 4, catH, catL,
                      (rt * 16 + lrow) * 16 + br * OO + lk * 4);
        }
    }
    __syncthreads();

    // ---- proj input layer (K=16 pad 32): wave wv -> jtile wv, 2 rowtiles
    {
        const f16x8* WF = (const f16x8*)(wsf + WS_W1 + 2 * 4096);
        f16x8 XH[2] = {}, XL[2] = {};
        if (lk < 2) {
            #pragma unroll
            for (int rt = 0; rt < 2; ++rt) {
                XH[rt] = *(const f16x8*)(catH + (rt * 16 + lrow) * 16 + lk * 8);
                XL[rt] = *(const f16x8*)(catL + (rt * 16 + lrow) * 16 + lk * 8);
            }
        }
        f32x4 acc[2] = {};
        const f16x8 wh = WF[wv * 64 + lane];
        #pragma unroll
        for (int rt = 0; rt < 2; ++rt) {
            acc[rt] = __builtin_amdgcn_mfma_f32_16x16x32_f16(wh, XH[rt], acc[rt], 0, 0, 0);
            acc[rt] = __builtin_amdgcn_mfma_f32_16x16x32_f16(wh, XL[rt], acc[rt], 0, 0, 0);
        }
        const int jb = wv * 16 + lk * 4;
        #pragma unroll
        for (int rt = 0; rt < 2; ++rt)
            epi_store(acc[rt], pb1, jb, hbuf[0][0], hbuf[0][1],
                      (rt * 16 + lrow) * ASTRB + jb);
    }
    __syncthreads();

    // ---- proj heavy layer (128x128): wave wv -> jtile wv, 2 rowtiles
    {
        const ushort* aH = hbuf[0][0];
        const ushort* aL = hbuf[0][1];
        const f16x8* WF = (const f16x8*)(wsf + WS_W2 + 2 * 16384);
        f32x4 acc[2] = {};
        #pragma unroll
        for (int ks = 0; ks < 4; ++ks) {
            const f16x8 wh = WF[(wv * 4 + ks) * 64 + lane];
            #pragma unroll
            for (int rt = 0; rt < 2; ++rt) {
                const int ab = (rt * 16 + lrow) * ASTRB + ks * 32 + lk * 8;
                const f16x8 xh = *(const f16x8*)(aH + ab);
                const f16x8 xl = *(const f16x8*)(aL + ab);
                acc[rt] = __builtin_amdgcn_mfma_f32_16x16x32_f16(wh, xh, acc[rt], 0, 0, 0);
                acc[rt] = __builtin_amdgcn_mfma_f32_16x16x32_f16(wh, xl, acc[rt], 0, 0, 0);
            }
        }
        const int jb = wv * 16 + lk * 4;
        #pragma unroll
        for (int rt = 0; rt < 2; ++rt)
            epi_store(acc[rt], pb2, jb, gbuf[0][0], gbuf[0][1],
                      (rt * 16 + lrow) * ASTRB + jb);
    }
    __syncthreads();

    // ---- proj output layer (128 -> 8): waves 0,1 -> rowtiles, dwordx4 store
    if (wv < 2) {
        const int rt = wv;
        const ushort* aH = gbuf[0][0];
        const ushort* aL = gbuf[0][1];
        const f16x8* WF = (const f16x8*)(wsf + WS_W3 + 2 * 2048);
        f32x4 acc = {};
        #pragma unroll
        for (int ks = 0; ks < 4; ++ks) {
            const int ab = (rt * 16 + lrow) * ASTRB + ks * 32 + lk * 8;
            const f16x8 xh = *(const f16x8*)(aH + ab);
            const f16x8 xl = *(const f16x8*)(aL + ab);
            const f16x8 wh = WF[ks * 64 + lane];
            acc = __builtin_amdgcn_mfma_f32_16x16x32_f16(wh, xh, acc, 0, 0, 0);
            acc = __builtin_amdgcn_mfma_f32_16x16x32_f16(wh, xl, acc, 0, 0, 0);
        }
        if (lk < 2) {
            const float4 bb = *(const float4*)(pb3 + lk * 4);
            float4 o;
            o.x = acc[0] + bb.x; o.y = acc[1] + bb.y;
            o.z = acc[2] + bb.z; o.w = acc[3] + bb.w;
            *(float4*)(out + (row0 + rt * 16 + lrow) * OO + lk * 4) = o;
        }
    }
}

extern "C" void kernel_launch(void* const* d_in, const int* in_sizes, int n_in,
                              void* d_out, int out_size, void* d_ws, size_t ws_size,
                              hipStream_t stream) {
    (void)in_sizes; (void)n_in; (void)out_size; (void)ws_size;
    const int*   adj  = (const int*)  d_in[0];
    const float* fop  = (const float*)d_in[1];
    const float* fmab = (const float*)d_in[2];
    const float* l0w1 = (const float*)d_in[3];
    const float* l0b1 = (const float*)d_in[4];
    const float* l0w2 = (const float*)d_in[5];
    const float* l0b2 = (const float*)d_in[6];
    const float* l0w3 = (const float*)d_in[7];
    const float* l0b3 = (const float*)d_in[8];
    const float* l1w1 = (const float*)d_in[9];
    const float* l1b1 = (const float*)d_in[10];
    const float* l1w2 = (const float*)d_in[11];
    const float* l1b2 = (const float*)d_in[12];
    const float* l1w3 = (const float*)d_in[13];
    const float* l1b3 = (const float*)d_in[14];
    const float* pw1  = (const float*)d_in[15];
    const float* pb1  = (const float*)d_in[16];
    const float* pw2  = (const float*)d_in[17];
    const float* pb2  = (const float*)d_in[18];
    const float* pw3  = (const float*)d_in[19];
    const float* pb3  = (const float*)d_in[20];
    float* out = (float*)d_out;
    ushort* wsf = (ushort*)d_ws;

    // 67584 weight elements -> 264 blocks
    prep_kernel<<<dim3(264), dim3(256), 0, stream>>>(
        l0w2, l1w2, pw2, l0w3, l1w3, pw3, l0w1, l1w1, pw1, wsf);

    const int grid = (BB * N_OPC) / TM;   // 512
    mlps_kernel<<<dim3(grid), dim3(512), 0, stream>>>(
        adj, fop, fmab,
        l0b1, l0b2, l0b3,
        l1b1, l1b2, l1b3,
        pb1, pb2, pb3,
        wsf, out);
}

// Round 9
// 18.472 us; speedup vs baseline: 1.5432x; 1.0849x over previous
//
#include <hip/hip_runtime.h>

// Problem constants
#define BB    32
#define N_OPC 512
#define N_MAC 64
#define FF    8
#define HH    128
#define OO    8
#define TM    32      // rows per block
#define ASTRB 136     // activation plane row stride (ushorts), 272B

typedef _Float16 f16x8 __attribute__((ext_vector_type(8)));
typedef _Float16 f16x4 __attribute__((ext_vector_type(4)));
typedef float    f32x4 __attribute__((ext_vector_type(4)));

// ws layout (ushort offsets), fp16 single plane. Frag element:
//   frag[(jt*KS+ks)*64+lane][i] = W[k = ks*32+(lane>>4)*8+i][j = jt*16+(lane&15)], zero-padded.
// Used as the MFMA *A* operand (weights-as-A swapped form).
#define WS_W2 0        // L*16384, L: 0=l0w2 1=l1w2 2=pw2   (8 jt x 4 ks)
#define WS_W3 49152    // L*2048,  L: 0=l0w3 1=l1w3 2=pw3   (1 jt x 4 ks, cols padded to 16)
#define WS_W1 55296    // L*4096,  L: 0=l0w1 1=l1w1 2=pw1   (8 jt x 1 ks, K padded to 32)

__device__ __forceinline__ float elu_f(float x) {
    return x > 0.0f ? x : (__expf(x) - 1.0f);
}
__device__ __forceinline__ void store_f16(float v, ushort* dst, int off) {
    const _Float16 h = (_Float16)v;
    dst[off] = __builtin_bit_cast(ushort, h);
}

// ---- weight prep: fp32 -> fp16 fragments (single plane) ----
__global__ void prep_kernel(const float* __restrict__ w20, const float* __restrict__ w21,
                            const float* __restrict__ w22,
                            const float* __restrict__ w30, const float* __restrict__ w31,
                            const float* __restrict__ w32,
                            const float* __restrict__ w10, const float* __restrict__ w11,
                            const float* __restrict__ w12,
                            ushort* __restrict__ ws)
{
    const int gid = blockIdx.x * 256 + threadIdx.x;
    if (gid < 3 * 16384) {                       // W2: 128x128
        const int layer = gid >> 14, idx = gid & 16383;
        const float* w = layer == 0 ? w20 : layer == 1 ? w21 : w22;
        const int k = idx >> 7, j = idx & 127;
        const float x = w[idx];
        const int ks = k >> 5, kk = k & 31, jt = j >> 4, jj = j & 15;
        const int lane = ((kk >> 3) << 4) | jj, i = kk & 7;
        const int off = (((jt * 4 + ks) * 64 + lane) << 3) + i;
        const _Float16 h = (_Float16)x;
        ws[WS_W2 + layer * 16384 + off] = __builtin_bit_cast(ushort, h);
    } else if (gid < 3 * 16384 + 3 * 2048) {     // W3: 128x8 padded to 16 cols
        const int g2 = gid - 3 * 16384;
        const int layer = g2 >> 11, idx = g2 & 2047;
        const float* w = layer == 0 ? w30 : layer == 1 ? w31 : w32;
        const int i = idx & 7, lane = (idx >> 3) & 63, ks = idx >> 9;
        const int k = ks * 32 + (lane >> 4) * 8 + i, j = lane & 15;
        const float x = (j < OO) ? w[k * OO + j] : 0.0f;
        const _Float16 h = (_Float16)x;
        ws[WS_W3 + layer * 2048 + idx] = __builtin_bit_cast(ushort, h);
    } else {                                     // W1: Kx128, K padded to 32
        const int g1 = gid - (3 * 16384 + 3 * 2048);
        const int layer = g1 >> 12, idx = g1 & 4095;
        const float* w = layer == 0 ? w10 : layer == 1 ? w11 : w12;
        const int i = idx & 7, lane = (idx >> 3) & 63, jt = idx >> 9;
        const int k = (lane >> 4) * 8 + i, j = jt * 16 + (lane & 15);
        const int Kr = (layer == 2) ? 16 : 8;
        const float x = (k < Kr) ? w[k * HH + j] : 0.0f;
        const _Float16 h = (_Float16)x;
        ws[WS_W1 + layer * 4096 + idx] = __builtin_bit_cast(ushort, h);
    }
}

// epilogue: acc (4 consecutive output features) + bias -> elu -> fp16 -> 1x ds_write_b64
__device__ __forceinline__ void epi_store(f32x4 a, const float* __restrict__ bias, int jb,
                                          ushort* __restrict__ dst, int off)
{
    const float4 bb = *(const float4*)(bias + jb);
    f16x4 v;
    v[0] = (_Float16)elu_f(a[0] + bb.x);
    v[1] = (_Float16)elu_f(a[1] + bb.y);
    v[2] = (_Float16)elu_f(a[2] + bb.z);
    v[3] = (_Float16)elu_f(a[3] + bb.w);
    *(f16x4*)(dst + off) = v;
}

__global__ __launch_bounds__(512, 4) void mlps_kernel(
    const int*   __restrict__ adj,
    const float* __restrict__ fop,
    const float* __restrict__ fmab,
    const float* __restrict__ l0b1, const float* __restrict__ l0b2, const float* __restrict__ l0b3,
    const float* __restrict__ l1b1, const float* __restrict__ l1b2, const float* __restrict__ l1b3,
    const float* __restrict__ pb1,  const float* __restrict__ pb2,  const float* __restrict__ pb3,
    const ushort* __restrict__ wsf,
    float* __restrict__ out)
{
    __shared__ __align__(16) ushort hbuf[2][TM * ASTRB];   // [br], single fp16 plane
    __shared__ __align__(16) ushort gbuf[2][TM * ASTRB];
    __shared__ float fmS[N_MAC * FF];
    __shared__ __align__(16) ushort xinF[TM * FF];
    __shared__ __align__(16) ushort xopF[TM * FF];
    __shared__ __align__(16) ushort catF[TM * 16];

    const int tid  = threadIdx.x;
    const int wv   = tid >> 6;
    const int lane = tid & 63;
    const int lrow = lane & 15;       // activation row within 16-row tile
    const int lk   = lane >> 4;       // k-octet / output-feature quad
    const int row0 = blockIdx.x * TM;
    const int b    = row0 / N_OPC;

    // ---- stage: machine feats (fp32), op feats (fp16)
    fmS[tid] = fmab[b * N_MAC * FF + tid];
    if (tid < TM * FF)
        store_f16(fop[row0 * FF + tid], xopF, tid);
    __syncthreads();

    // ---- aggregation: xin[r][f] = sum_m adj[r][m] * fm[m][f]
    if (tid < TM * FF) {
        const int r = tid >> 3, f = tid & 7;
        const int* arow = adj + (row0 + r) * N_MAC;
        float a = 0.0f;
        #pragma unroll
        for (int m4 = 0; m4 < N_MAC; m4 += 4) {
            const int4 av = *(const int4*)(arow + m4);
            a = fmaf((float)av.x, fmS[(m4 + 0) * FF + f], a);
            a = fmaf((float)av.y, fmS[(m4 + 1) * FF + f], a);
            a = fmaf((float)av.z, fmS[(m4 + 2) * FF + f], a);
            a = fmaf((float)av.w, fmS[(m4 + 3) * FF + f], a);
        }
        store_f16(a, xinF, tid);
    }
    __syncthreads();

    // ---- input layers (K=8 pad 32): waves 0-3 br0, 4-7 br1; 2 jtiles, 2 rowtiles each
    {
        const int br = wv >> 2, jt0 = (wv & 3) * 2;
        const ushort* xF = br ? xopF : xinF;
        const f16x8* WF = (const f16x8*)(wsf + WS_W1 + br * 4096);
        const float* b1 = br ? l1b1 : l0b1;
        f16x8 X[2] = {};
        if (lk == 0) {
            #pragma unroll
            for (int rt = 0; rt < 2; ++rt)
                X[rt] = *(const f16x8*)(xF + (rt * 16 + lrow) * 8);
        }
        f32x4 acc[2][2] = {};
        #pragma unroll
        for (int jtl = 0; jtl < 2; ++jtl) {
            const f16x8 wh = WF[(jt0 + jtl) * 64 + lane];
            #pragma unroll
            for (int rt = 0; rt < 2; ++rt)
                acc[jtl][rt] = __builtin_amdgcn_mfma_f32_16x16x32_f16(wh, X[rt], acc[jtl][rt], 0, 0, 0);
        }
        ushort* dF = hbuf[br];
        #pragma unroll
        for (int jtl = 0; jtl < 2; ++jtl) {
            const int jb = (jt0 + jtl) * 16 + lk * 4;
            #pragma unroll
            for (int rt = 0; rt < 2; ++rt)
                epi_store(acc[jtl][rt], b1, jb, dF, (rt * 16 + lrow) * ASTRB + jb);
        }
    }
    __syncthreads();

    // ---- heavy layers (128x128): waves 0-3 br0, 4-7 br1; 2 jtiles x 2 rowtiles
    {
        const int br = wv >> 2, jt0 = (wv & 3) * 2;
        const ushort* aF = hbuf[br];
        const f16x8* WF = (const f16x8*)(wsf + WS_W2 + br * 16384);
        f32x4 acc[2][2] = {};
        #pragma unroll
        for (int ks = 0; ks < 4; ++ks) {
            f16x8 x[2];
            #pragma unroll
            for (int rt = 0; rt < 2; ++rt)
                x[rt] = *(const f16x8*)(aF + (rt * 16 + lrow) * ASTRB + ks * 32 + lk * 8);
            #pragma unroll
            for (int jtl = 0; jtl < 2; ++jtl) {
                const f16x8 wh = WF[((jt0 + jtl) * 4 + ks) * 64 + lane];
                #pragma unroll
                for (int rt = 0; rt < 2; ++rt)
                    acc[jtl][rt] = __builtin_amdgcn_mfma_f32_16x16x32_f16(wh, x[rt], acc[jtl][rt], 0, 0, 0);
            }
        }
        const float* b2 = br ? l1b2 : l0b2;
        ushort* dF = gbuf[br];
        #pragma unroll
        for (int jtl = 0; jtl < 2; ++jtl) {
            const int jb = (jt0 + jtl) * 16 + lk * 4;
            #pragma unroll
            for (int rt = 0; rt < 2; ++rt)
                epi_store(acc[jtl][rt], b2, jb, dF, (rt * 16 + lrow) * ASTRB + jb);
        }
    }
    __syncthreads();

    // ---- branch output layers (128 -> 8 pad 16): waves 0-3
    if (wv < 4) {
        const int br = wv >> 1, rt = wv & 1;
        const ushort* aF = gbuf[br];
        const f16x8* WF = (const f16x8*)(wsf + WS_W3 + br * 2048);
        f32x4 acc = {};
        #pragma unroll
        for (int ks = 0; ks < 4; ++ks) {
            const f16x8 x = *(const f16x8*)(aF + (rt * 16 + lrow) * ASTRB + ks * 32 + lk * 8);
            const f16x8 wh = WF[ks * 64 + lane];
            acc = __builtin_amdgcn_mfma_f32_16x16x32_f16(wh, x, acc, 0, 0, 0);
        }
        if (lk < 2) {   // valid output features j = lk*4 .. lk*4+3 (0..7)
            const float* b3 = br ? l1b3 : l0b3;
            epi_store(acc, b3, lk * 4, catF, (rt * 16 + lrow) * 16 + br * OO + lk * 4);
        }
    }
    __syncthreads();

    // ---- proj input layer (K=16 pad 32): wave wv -> jtile wv, 2 rowtiles
    {
        const f16x8* WF = (const f16x8*)(wsf + WS_W1 + 2 * 4096);
        f16x8 X[2] = {};
        if (lk < 2) {
            #pragma unroll
            for (int rt = 0; rt < 2; ++rt)
                X[rt] = *(const f16x8*)(catF + (rt * 16 + lrow) * 16 + lk * 8);
        }
        f32x4 acc[2] = {};
        const f16x8 wh = WF[wv * 64 + lane];
        #pragma unroll
        for (int rt = 0; rt < 2; ++rt)
            acc[rt] = __builtin_amdgcn_mfma_f32_16x16x32_f16(wh, X[rt], acc[rt], 0, 0, 0);
        const int jb = wv * 16 + lk * 4;
        #pragma unroll
        for (int rt = 0; rt < 2; ++rt)
            epi_store(acc[rt], pb1, jb, hbuf[0], (rt * 16 + lrow) * ASTRB + jb);
    }
    __syncthreads();

    // ---- proj heavy layer (128x128): wave wv -> jtile wv, 2 rowtiles
    {
        const ushort* aF = hbuf[0];
        const f16x8* WF = (const f16x8*)(wsf + WS_W2 + 2 * 16384);
        f32x4 acc[2] = {};
        #pragma unroll
        for (int ks = 0; ks < 4; ++ks) {
            const f16x8 wh = WF[(wv * 4 + ks) * 64 + lane];
            #pragma unroll
            for (int rt = 0; rt < 2; ++rt) {
                const f16x8 x = *(const f16x8*)(aF + (rt * 16 + lrow) * ASTRB + ks * 32 + lk * 8);
                acc[rt] = __builtin_amdgcn_mfma_f32_16x16x32_f16(wh, x, acc[rt], 0, 0, 0);
            }
        }
        const int jb = wv * 16 + lk * 4;
        #pragma unroll
        for (int rt = 0; rt < 2; ++rt)
            epi_store(acc[rt], pb2, jb, gbuf[0], (rt * 16 + lrow) * ASTRB + jb);
    }
    __syncthreads();

    // ---- proj output layer (128 -> 8): waves 0,1 -> rowtiles, dwordx4 store
    if (wv < 2) {
        const int rt = wv;
        const ushort* aF = gbuf[0];
        const f16x8* WF = (const f16x8*)(wsf + WS_W3 + 2 * 2048);
        f32x4 acc = {};
        #pragma unroll
        for (int ks = 0; ks < 4; ++ks) {
            const f16x8 x = *(const f16x8*)(aF + (rt * 16 + lrow) * ASTRB + ks * 32 + lk * 8);
            const f16x8 wh = WF[ks * 64 + lane];
            acc = __builtin_amdgcn_mfma_f32_16x16x32_f16(wh, x, acc, 0, 0, 0);
        }
        if (lk < 2) {
            const float4 bb = *(const float4*)(pb3 + lk * 4);
            float4 o;
            o.x = acc[0] + bb.x; o.y = acc[1] + bb.y;
            o.z = acc[2] + bb.z; o.w = acc[3] + bb.w;
            *(float4*)(out + (row0 + rt * 16 + lrow) * OO + lk * 4) = o;
        }
    }
}

extern "C" void kernel_launch(void* const* d_in, const int* in_sizes, int n_in,
                              void* d_out, int out_size, void* d_ws, size_t ws_size,
                              hipStream_t stream) {
    (void)in_sizes; (void)n_in; (void)out_size; (void)ws_size;
    const int*   adj  = (const int*)  d_in[0];
    const float* fop  = (const float*)d_in[1];
    const float* fmab = (const float*)d_in[2];
    const float* l0w1 = (const float*)d_in[3];
    const float* l0b1 = (const float*)d_in[4];
    const float* l0w2 = (const float*)d_in[5];
    const float* l0b2 = (const float*)d_in[6];
    const float* l0w3 = (const float*)d_in[7];
    const float* l0b3 = (const float*)d_in[8];
    const float* l1w1 = (const float*)d_in[9];
    const float* l1b1 = (const float*)d_in[10];
    const float* l1w2 = (const float*)d_in[11];
    const float* l1b2 = (const float*)d_in[12];
    const float* l1w3 = (const float*)d_in[13];
    const float* l1b3 = (const float*)d_in[14];
    const float* pw1  = (const float*)d_in[15];
    const float* pb1  = (const float*)d_in[16];
    const float* pw2  = (const float*)d_in[17];
    const float* pb2  = (const float*)d_in[18];
    const float* pw3  = (const float*)d_in[19];
    const float* pb3  = (const float*)d_in[20];
    float* out = (float*)d_out;
    ushort* wsf = (ushort*)d_ws;

    // 67584 weight elements -> 264 blocks
    prep_kernel<<<dim3(264), dim3(256), 0, stream>>>(
        l0w2, l1w2, pw2, l0w3, l1w3, pw3, l0w1, l1w1, pw1, wsf);

    const int grid = (BB * N_OPC) / TM;   // 512
    mlps_kernel<<<dim3(grid), dim3(512), 0, stream>>>(
        adj, fop, fmab,
        l0b1, l0b2, l0b3,
        l1b1, l1b2, l1b3,
        pb1, pb2, pb3,
        wsf, out);
}